// Round 9
// baseline (665.323 us; speedup 1.0000x reference)
//
#include <hip/hip_runtime.h>
#include <hip/hip_bf16.h>

// AttributeGNN, bf16 MFMA, fp32 accumulate. B=16384, A=16, D=256.
// R9: R8 minus the F bounce buffer -> LDS 64KB -> 2 blocks/CU (correct
// __launch_bounds__(512,4)); attr stored directly from acc (nt); edgeT loads nt.

typedef __bf16 bf16_t;
typedef __bf16 bf16x4 __attribute__((ext_vector_type(4)));
typedef __bf16 bf16x8 __attribute__((ext_vector_type(8)));
typedef float f32x4 __attribute__((ext_vector_type(4)));

#define NB 16384
#define NA 16
#define ND 256

// XOR swizzle for bf16 LDS tiles [32][256]: 8-row stripes spread across 8
// distinct 16B slots; 16-lane column reads -> 2-way (free per m136).
__device__ __forceinline__ int swz(int r, int c) {
    return r * 256 + (c ^ ((r & 7) << 3));
}

__device__ __forceinline__ bf16x8 cvt8(f32x4 a, f32x4 b) {
    bf16x8 r;
    r[0] = (bf16_t)a.x; r[1] = (bf16_t)a.y; r[2] = (bf16_t)a.z; r[3] = (bf16_t)a.w;
    r[4] = (bf16_t)b.x; r[5] = (bf16_t)b.y; r[6] = (bf16_t)b.z; r[7] = (bf16_t)b.w;
    return r;
}

// 32(M) x 256(K) x 32(N-slice) GEMM, B held in registers (W[ni][ks]).
// C/D layout per m89: col = lane&15, row = (lane>>4)*4 + j.
__device__ __forceinline__ void gemm32r(const bf16_t* a_lds, const bf16x8 (&W)[2][8],
                                        f32x4 acc[2][2], int lane)
{
    const int lr = lane & 15, lhi = lane >> 4;
#pragma unroll
    for (int ks = 0; ks < 8; ++ks) {
        const int kc = ks * 32 + lhi * 8;
        bf16x8 af0 = *(const bf16x8*)&a_lds[swz(lr, kc)];
        bf16x8 af1 = *(const bf16x8*)&a_lds[swz(16 + lr, kc)];
        acc[0][0] = __builtin_amdgcn_mfma_f32_16x16x32_bf16(af0, W[0][ks], acc[0][0], 0, 0, 0);
        acc[1][0] = __builtin_amdgcn_mfma_f32_16x16x32_bf16(af1, W[0][ks], acc[1][0], 0, 0, 0);
        acc[0][1] = __builtin_amdgcn_mfma_f32_16x16x32_bf16(af0, W[1][ks], acc[0][1], 0, 0, 0);
        acc[1][1] = __builtin_amdgcn_mfma_f32_16x16x32_bf16(af1, W[1][ks], acc[1][1], 0, 0, 0);
    }
}

// Same, B from global fragment layout (L2-resident), depth-2 register pipeline.
__device__ __forceinline__ void gemm32g(const bf16_t* a_lds, const bf16_t* __restrict__ Bf,
                                        f32x4 acc[2][2], int lane, int wc)
{
    const int lr = lane & 15, lhi = lane >> 4;
    const bf16_t* bp = Bf + (size_t)wc * 16 * 512 + lane * 8;
    bf16x8 b0a = *(const bf16x8*)&bp[0 * 512];
    bf16x8 b1a = *(const bf16x8*)&bp[8 * 512];
    bf16x8 b0b = *(const bf16x8*)&bp[1 * 512];
    bf16x8 b1b = *(const bf16x8*)&bp[9 * 512];
#pragma unroll
    for (int ks = 0; ks < 8; ++ks) {
        const int kc = ks * 32 + lhi * 8;
        bf16x8 af0 = *(const bf16x8*)&a_lds[swz(lr, kc)];
        bf16x8 af1 = *(const bf16x8*)&a_lds[swz(16 + lr, kc)];
        bf16x8 c0 = (ks & 1) ? b0b : b0a;
        bf16x8 c1 = (ks & 1) ? b1b : b1a;
        acc[0][0] = __builtin_amdgcn_mfma_f32_16x16x32_bf16(af0, c0, acc[0][0], 0, 0, 0);
        acc[1][0] = __builtin_amdgcn_mfma_f32_16x16x32_bf16(af1, c0, acc[1][0], 0, 0, 0);
        acc[0][1] = __builtin_amdgcn_mfma_f32_16x16x32_bf16(af0, c1, acc[0][1], 0, 0, 0);
        acc[1][1] = __builtin_amdgcn_mfma_f32_16x16x32_bf16(af1, c1, acc[1][1], 0, 0, 0);
        if (ks + 2 < 8) {
            if (ks & 1) {
                b0b = *(const bf16x8*)&bp[(ks + 2) * 512];
                b1b = *(const bf16x8*)&bp[(8 + ks + 2) * 512];
            } else {
                b0a = *(const bf16x8*)&bp[(ks + 2) * 512];
                b1a = *(const bf16x8*)&bp[(8 + ks + 2) * 512];
            }
        }
    }
}

// ---- W_agg [256][512] fp32 -> W1f / W2f fragment layout (bf16).
__global__ void prep_wfrag(const float* __restrict__ W,
                           bf16_t* __restrict__ W1f, bf16_t* __restrict__ W2f)
{
    int t = blockIdx.x * 256 + threadIdx.x;
    int lane = t & 63;
    int ks = (t >> 6) & 7;
    int nt = (t >> 9) & 15;
    int half = t >> 13;
    int row = nt * 16 + (lane & 15);
    int col = ks * 32 + (lane >> 4) * 8;
    const float* src = W + (size_t)row * 512 + half * 256 + col;
    bf16_t* dst = (half ? W2f : W1f) + ((nt * 8 + ks) * 64 + lane) * 8;
    bf16x8 v;
#pragma unroll
    for (int m = 0; m < 8; ++m) v[m] = (bf16_t)src[m];
    *(bf16x8*)dst = v;
}

// ---- P[a][i][j] fp32 -> Pt[a][j][i] bf16 via LDS transpose.
__global__ void transpose_P(const float* __restrict__ Pf, const float* __restrict__ Pb,
                            bf16_t* __restrict__ Pft, bf16_t* __restrict__ Pbt)
{
    __shared__ float t[32][33];
    int blk = blockIdx.x;
    int mat = blk >> 10;
    int rest = blk & 1023;
    int a = rest >> 6;
    int tile = rest & 63;
    int i0 = (tile >> 3) * 32;
    int j0 = (tile & 7) * 32;
    const float* src = (mat ? Pb : Pf) + a * 65536;
    bf16_t* dst = (mat ? Pbt : Pft) + a * 65536;
    int r = threadIdx.x >> 5, c = threadIdx.x & 31;
#pragma unroll
    for (int it = 0; it < 4; ++it)
        t[r + 8 * it][c] = src[(i0 + r + 8 * it) * 256 + j0 + c];
    __syncthreads();
#pragma unroll
    for (int it = 0; it < 4; ++it)
        dst[(j0 + r + 8 * it) * 256 + i0 + c] = (bf16_t)t[c][r + 8 * it];
}

// ---- row-major bf16 [16][256][256] -> fragment layout.
__global__ void prep_pfrag(const bf16_t* __restrict__ Pt, bf16_t* __restrict__ Pfr)
{
    int t = blockIdx.x * 256 + threadIdx.x;
    int lane = t & 63;
    int ks = (t >> 6) & 7;
    int nt = (t >> 9) & 15;
    int a = t >> 13;
    bf16x8 v = *(const bf16x8*)&Pt[(size_t)a * 65536 + (nt * 16 + (lane & 15)) * 256 + ks * 32 + (lane >> 4) * 8];
    *(bf16x8*)&Pfr[(size_t)a * 65536 + ((nt * 8 + ks) * 64 + lane) * 8] = v;
}

// ---- edge [b][a][d] fp32 -> edgeT [a][b][d] bf16 (linear reads).
__global__ void edge_tr(const float* __restrict__ edge, bf16_t* __restrict__ edgeT)
{
    size_t t = (size_t)blockIdx.x * 256 + threadIdx.x;
    size_t b = t >> 9;
    int a = (int)((t >> 5) & 15);
    int d8 = (int)(t & 31);
    const float* src = edge + (b << 12) + (a << 8) + (d8 << 3);
    f32x4 v0 = *(const f32x4*)src;
    f32x4 v1 = *(const f32x4*)(src + 4);
    *(bf16x8*)&edgeT[(((size_t)a << 14) + b) * 256 + (d8 << 3)] = cvt8(v0, v1);
}

// ---- fused main. LDS 64KB -> 2 blocks/CU.
__global__ __launch_bounds__(512, 4)
void fused_main(const float* __restrict__ img, const float* __restrict__ bias,
                const bf16_t* __restrict__ edgeT,
                const bf16_t* __restrict__ W1f, const bf16_t* __restrict__ W2f,
                const bf16_t* __restrict__ Pff, const bf16_t* __restrict__ Pbf,
                const float* __restrict__ sw, float* __restrict__ out)
{
    __shared__ bf16_t E[2][32 * 256];   // 2 x 16 KB edge dbuf
    __shared__ bf16_t G[32 * 256];      // 16 KB agg
    __shared__ bf16_t R[32 * 256];      // 16 KB attr bf16

    const int tid = threadIdx.x;
    const int lane = tid & 63;
    const int wc = tid >> 6;            // 0..7: 32-col slice
    const int lr = lane & 15;
    const int lhi = lane >> 4;
    const int brow0 = blockIdx.x * 32;
    const int sr = tid >> 4;            // staging row 0..31
    const int c16 = (tid & 15) * 16;    // staging col base

    // ---- prologue: img -> E[0] (bf16 swz)
    {
        const float* ip = img + (size_t)(brow0 + sr) * ND + c16;
        f32x4 v0 = *(const f32x4*)(ip + 0), v1 = *(const f32x4*)(ip + 4);
        f32x4 v2 = *(const f32x4*)(ip + 8), v3 = *(const f32x4*)(ip + 12);
        *(bf16x8*)&E[0][swz(sr, c16)] = cvt8(v0, v1);
        *(bf16x8*)&E[0][swz(sr, c16 + 8)] = cvt8(v2, v3);
    }
    __syncthreads();

    // ---- T = img @ W1^T + bias (W1 in regs, then overwritten by W2)
    bf16x8 Wr[2][8];
#pragma unroll
    for (int ni = 0; ni < 2; ++ni)
#pragma unroll
        for (int ks = 0; ks < 8; ++ks)
            Wr[ni][ks] = *(const bf16x8*)&W1f[(((wc * 2 + ni) * 8 + ks) * 64 + lane) * 8];

    f32x4 T[2][2];
#pragma unroll
    for (int ni = 0; ni < 2; ++ni) {
        float bz = bias[wc * 32 + ni * 16 + lr];
        T[0][ni] = (f32x4){bz, bz, bz, bz};
        T[1][ni] = (f32x4){bz, bz, bz, bz};
    }
    gemm32r(&E[0][0], Wr, T, lane);

#pragma unroll
    for (int ni = 0; ni < 2; ++ni)
#pragma unroll
        for (int ks = 0; ks < 8; ++ks)
            Wr[ni][ks] = *(const bf16x8*)&W2f[(((wc * 2 + ni) * 8 + ks) * 64 + lane) * 8];
    __syncthreads();                    // E[0] free

    // ---- edge(a=0) -> E[0]
    {
        const bf16_t* ep = edgeT + ((size_t)0 * NB + brow0 + sr) * ND + c16;
        *(bf16x8*)&E[0][swz(sr, c16)] = __builtin_nontemporal_load((const bf16x8*)ep);
        *(bf16x8*)&E[0][swz(sr, c16 + 8)] = __builtin_nontemporal_load((const bf16x8*)(ep + 8));
    }
    __syncthreads();

    f32x4 indiv[2][2];
#pragma unroll
    for (int mi = 0; mi < 2; ++mi)
#pragma unroll
        for (int ni = 0; ni < 2; ++ni)
            indiv[mi][ni] = (f32x4){0.f, 0.f, 0.f, 0.f};

    for (int a = 0; a < NA; ++a) {
        const int cur = a & 1;
        const bool pf = (a + 1 < NA);
        f32x4 acc[2][2];

        // ---- phase 1: issue edge(a+1) loads; GEMM1 = T + edge @ W2^T (regs B)
        bf16x8 elo, ehi;
        if (pf) {
            const bf16_t* ep = edgeT + ((size_t)(a + 1) * NB + brow0 + sr) * ND + c16;
            elo = __builtin_nontemporal_load((const bf16x8*)ep);
            ehi = __builtin_nontemporal_load((const bf16x8*)(ep + 8));
        }
#pragma unroll
        for (int mi = 0; mi < 2; ++mi)
#pragma unroll
            for (int ni = 0; ni < 2; ++ni)
                acc[mi][ni] = T[mi][ni];
        gemm32r(&E[cur][0], Wr, acc, lane);
#pragma unroll
        for (int mi = 0; mi < 2; ++mi)
#pragma unroll
            for (int ni = 0; ni < 2; ++ni)
#pragma unroll
                for (int j = 0; j < 4; ++j)
                    G[swz(mi * 16 + lhi * 4 + j, wc * 32 + ni * 16 + lr)] = (bf16_t)acc[mi][ni][j];
        if (pf) {   // commit edge(a+1); HBM/L3 latency hidden under GEMM1
            *(bf16x8*)&E[cur ^ 1][swz(sr, c16)] = elo;
            *(bf16x8*)&E[cur ^ 1][swz(sr, c16 + 8)] = ehi;
        }
        __syncthreads();

        // ---- phase 2: attr = agg @ Pf[a] -> R (bf16 swz) + direct nt fp32 out
#pragma unroll
        for (int mi = 0; mi < 2; ++mi)
#pragma unroll
            for (int ni = 0; ni < 2; ++ni)
                acc[mi][ni] = (f32x4){0.f, 0.f, 0.f, 0.f};
        gemm32g(&G[0], Pff + (size_t)a * 65536, acc, lane, wc);
        {
            float* op = out + (size_t)brow0 * (NA * ND) + (size_t)a * ND;
#pragma unroll
            for (int mi = 0; mi < 2; ++mi)
#pragma unroll
                for (int ni = 0; ni < 2; ++ni)
#pragma unroll
                    for (int j = 0; j < 4; ++j) {
                        int r = mi * 16 + lhi * 4 + j;
                        int c = wc * 32 + ni * 16 + lr;
                        float v = acc[mi][ni][j];
                        R[swz(r, c)] = (bf16_t)v;
                        __builtin_nontemporal_store(v, &op[(size_t)r * (NA * ND) + c]);
                    }
        }
        __syncthreads();

        // ---- phase 3: proj = relu(attr @ Pb[a]); indiv += proj * sw[a]
#pragma unroll
        for (int mi = 0; mi < 2; ++mi)
#pragma unroll
            for (int ni = 0; ni < 2; ++ni)
                acc[mi][ni] = (f32x4){0.f, 0.f, 0.f, 0.f};
        gemm32g(&R[0], Pbf + (size_t)a * 65536, acc, lane, wc);
        const float swa = sw[a];
#pragma unroll
        for (int mi = 0; mi < 2; ++mi)
#pragma unroll
            for (int ni = 0; ni < 2; ++ni)
#pragma unroll
                for (int j = 0; j < 4; ++j)
                    indiv[mi][ni][j] += fmaxf(acc[mi][ni][j], 0.f) * swa;
        __syncthreads();
    }

    // ---- individual_embeddings
#pragma unroll
    for (int mi = 0; mi < 2; ++mi)
#pragma unroll
        for (int ni = 0; ni < 2; ++ni)
#pragma unroll
            for (int j = 0; j < 4; ++j) {
                int r = mi * 16 + lhi * 4 + j;
                int c = wc * 32 + ni * 16 + lr;
                __builtin_nontemporal_store(indiv[mi][ni][j],
                    &out[(size_t)NB * NA * ND + (size_t)(brow0 + r) * ND + c]);
            }
}

extern "C" void kernel_launch(void* const* d_in, const int* in_sizes, int n_in,
                              void* d_out, int out_size, void* d_ws, size_t ws_size,
                              hipStream_t stream)
{
    const float* img  = (const float*)d_in[0];
    const float* edge = (const float*)d_in[1];
    const float* Wagg = (const float*)d_in[2];
    const float* bagg = (const float*)d_in[3];
    const float* Pf   = (const float*)d_in[4];
    const float* Pb   = (const float*)d_in[5];
    const float* sw   = (const float*)d_in[6];
    float* out = (float*)d_out;

    char* ws = (char*)d_ws;
    bf16_t* W1f = (bf16_t*)(ws);                   // 128 KB fragment layout
    bf16_t* W2f = (bf16_t*)(ws + 131072);          // 128 KB
    bf16_t* Pff = (bf16_t*)(ws + 262144);          // 2 MB
    bf16_t* Pbf = (bf16_t*)(ws + 2359296);         // 2 MB
    bf16_t* edT = (bf16_t*)(ws + 4456448);         // 134.2 MB [a][b][d] bf16
    // temps alias edT (dead before edge_tr runs; stream-ordered)
    bf16_t* Ptf = (bf16_t*)(ws + 4456448);         // 2 MB row-major temp
    bf16_t* Ptb = (bf16_t*)(ws + 6553600);         // 2 MB row-major temp

    prep_wfrag<<<64, 256, 0, stream>>>(Wagg, W1f, W2f);
    transpose_P<<<2048, 256, 0, stream>>>(Pf, Pb, Ptf, Ptb);
    prep_pfrag<<<512, 256, 0, stream>>>(Ptf, Pff);
    prep_pfrag<<<512, 256, 0, stream>>>(Ptb, Pbf);
    edge_tr<<<32768, 256, 0, stream>>>(edge, edT);
    fused_main<<<NB / 32, 512, 0, stream>>>(img, bagg, edT, W1f, W2f, Pff, Pbf, sw, out);
}

// Round 10
// 545.422 us; speedup vs baseline: 1.2198x; 1.2198x over previous
//
#include <hip/hip_runtime.h>
#include <hip/hip_bf16.h>

// AttributeGNN, bf16 MFMA, fp32 accumulate. B=16384, A=16, D=256.
// R10: R9 with (1) attr stored full-line in phase 3 via R readback (nt OK),
// (2) edgeT loads plain (L3-resident; nt defeated it in R9 -> 973MB FETCH),
// (3) swz mask widened to (r&15)<<3 -> GEMM A-reads bank-conflict-free.

typedef __bf16 bf16_t;
typedef __bf16 bf16x4 __attribute__((ext_vector_type(4)));
typedef __bf16 bf16x8 __attribute__((ext_vector_type(8)));
typedef float f32x4 __attribute__((ext_vector_type(4)));

#define NB 16384
#define NA 16
#define ND 256

// XOR swizzle for bf16 LDS tiles [32][256]: slot = chunk ^ (row&15) is a full
// permutation over the 32 8-elem chunks -> 2 lanes/bank (free) on A-reads.
__device__ __forceinline__ int swz(int r, int c) {
    return r * 256 + (c ^ ((r & 15) << 3));
}

__device__ __forceinline__ bf16x8 cvt8(f32x4 a, f32x4 b) {
    bf16x8 r;
    r[0] = (bf16_t)a.x; r[1] = (bf16_t)a.y; r[2] = (bf16_t)a.z; r[3] = (bf16_t)a.w;
    r[4] = (bf16_t)b.x; r[5] = (bf16_t)b.y; r[6] = (bf16_t)b.z; r[7] = (bf16_t)b.w;
    return r;
}

// 32(M) x 256(K) x 32(N-slice) GEMM, B held in registers (W[ni][ks]).
// C/D layout per m89: col = lane&15, row = (lane>>4)*4 + j.
__device__ __forceinline__ void gemm32r(const bf16_t* a_lds, const bf16x8 (&W)[2][8],
                                        f32x4 acc[2][2], int lane)
{
    const int lr = lane & 15, lhi = lane >> 4;
#pragma unroll
    for (int ks = 0; ks < 8; ++ks) {
        const int kc = ks * 32 + lhi * 8;
        bf16x8 af0 = *(const bf16x8*)&a_lds[swz(lr, kc)];
        bf16x8 af1 = *(const bf16x8*)&a_lds[swz(16 + lr, kc)];
        acc[0][0] = __builtin_amdgcn_mfma_f32_16x16x32_bf16(af0, W[0][ks], acc[0][0], 0, 0, 0);
        acc[1][0] = __builtin_amdgcn_mfma_f32_16x16x32_bf16(af1, W[0][ks], acc[1][0], 0, 0, 0);
        acc[0][1] = __builtin_amdgcn_mfma_f32_16x16x32_bf16(af0, W[1][ks], acc[0][1], 0, 0, 0);
        acc[1][1] = __builtin_amdgcn_mfma_f32_16x16x32_bf16(af1, W[1][ks], acc[1][1], 0, 0, 0);
    }
}

// Same, B from global fragment layout (L2-resident), depth-2 register pipeline.
__device__ __forceinline__ void gemm32g(const bf16_t* a_lds, const bf16_t* __restrict__ Bf,
                                        f32x4 acc[2][2], int lane, int wc)
{
    const int lr = lane & 15, lhi = lane >> 4;
    const bf16_t* bp = Bf + (size_t)wc * 16 * 512 + lane * 8;
    bf16x8 b0a = *(const bf16x8*)&bp[0 * 512];
    bf16x8 b1a = *(const bf16x8*)&bp[8 * 512];
    bf16x8 b0b = *(const bf16x8*)&bp[1 * 512];
    bf16x8 b1b = *(const bf16x8*)&bp[9 * 512];
#pragma unroll
    for (int ks = 0; ks < 8; ++ks) {
        const int kc = ks * 32 + lhi * 8;
        bf16x8 af0 = *(const bf16x8*)&a_lds[swz(lr, kc)];
        bf16x8 af1 = *(const bf16x8*)&a_lds[swz(16 + lr, kc)];
        bf16x8 c0 = (ks & 1) ? b0b : b0a;
        bf16x8 c1 = (ks & 1) ? b1b : b1a;
        acc[0][0] = __builtin_amdgcn_mfma_f32_16x16x32_bf16(af0, c0, acc[0][0], 0, 0, 0);
        acc[1][0] = __builtin_amdgcn_mfma_f32_16x16x32_bf16(af1, c0, acc[1][0], 0, 0, 0);
        acc[0][1] = __builtin_amdgcn_mfma_f32_16x16x32_bf16(af0, c1, acc[0][1], 0, 0, 0);
        acc[1][1] = __builtin_amdgcn_mfma_f32_16x16x32_bf16(af1, c1, acc[1][1], 0, 0, 0);
        if (ks + 2 < 8) {
            if (ks & 1) {
                b0b = *(const bf16x8*)&bp[(ks + 2) * 512];
                b1b = *(const bf16x8*)&bp[(8 + ks + 2) * 512];
            } else {
                b0a = *(const bf16x8*)&bp[(ks + 2) * 512];
                b1a = *(const bf16x8*)&bp[(8 + ks + 2) * 512];
            }
        }
    }
}

// ---- W_agg [256][512] fp32 -> W1f / W2f fragment layout (bf16).
__global__ void prep_wfrag(const float* __restrict__ W,
                           bf16_t* __restrict__ W1f, bf16_t* __restrict__ W2f)
{
    int t = blockIdx.x * 256 + threadIdx.x;
    int lane = t & 63;
    int ks = (t >> 6) & 7;
    int nt = (t >> 9) & 15;
    int half = t >> 13;
    int row = nt * 16 + (lane & 15);
    int col = ks * 32 + (lane >> 4) * 8;
    const float* src = W + (size_t)row * 512 + half * 256 + col;
    bf16_t* dst = (half ? W2f : W1f) + ((nt * 8 + ks) * 64 + lane) * 8;
    bf16x8 v;
#pragma unroll
    for (int m = 0; m < 8; ++m) v[m] = (bf16_t)src[m];
    *(bf16x8*)dst = v;
}

// ---- P[a][i][j] fp32 -> Pt[a][j][i] bf16 via LDS transpose.
__global__ void transpose_P(const float* __restrict__ Pf, const float* __restrict__ Pb,
                            bf16_t* __restrict__ Pft, bf16_t* __restrict__ Pbt)
{
    __shared__ float t[32][33];
    int blk = blockIdx.x;
    int mat = blk >> 10;
    int rest = blk & 1023;
    int a = rest >> 6;
    int tile = rest & 63;
    int i0 = (tile >> 3) * 32;
    int j0 = (tile & 7) * 32;
    const float* src = (mat ? Pb : Pf) + a * 65536;
    bf16_t* dst = (mat ? Pbt : Pft) + a * 65536;
    int r = threadIdx.x >> 5, c = threadIdx.x & 31;
#pragma unroll
    for (int it = 0; it < 4; ++it)
        t[r + 8 * it][c] = src[(i0 + r + 8 * it) * 256 + j0 + c];
    __syncthreads();
#pragma unroll
    for (int it = 0; it < 4; ++it)
        dst[(j0 + r + 8 * it) * 256 + i0 + c] = (bf16_t)t[c][r + 8 * it];
}

// ---- row-major bf16 [16][256][256] -> fragment layout.
__global__ void prep_pfrag(const bf16_t* __restrict__ Pt, bf16_t* __restrict__ Pfr)
{
    int t = blockIdx.x * 256 + threadIdx.x;
    int lane = t & 63;
    int ks = (t >> 6) & 7;
    int nt = (t >> 9) & 15;
    int a = t >> 13;
    bf16x8 v = *(const bf16x8*)&Pt[(size_t)a * 65536 + (nt * 16 + (lane & 15)) * 256 + ks * 32 + (lane >> 4) * 8];
    *(bf16x8*)&Pfr[(size_t)a * 65536 + ((nt * 8 + ks) * 64 + lane) * 8] = v;
}

// ---- edge [b][a][d] fp32 -> edgeT [a][b][d] bf16 (linear reads).
__global__ void edge_tr(const float* __restrict__ edge, bf16_t* __restrict__ edgeT)
{
    size_t t = (size_t)blockIdx.x * 256 + threadIdx.x;
    size_t b = t >> 9;
    int a = (int)((t >> 5) & 15);
    int d8 = (int)(t & 31);
    const float* src = edge + (b << 12) + (a << 8) + (d8 << 3);
    f32x4 v0 = *(const f32x4*)src;
    f32x4 v1 = *(const f32x4*)(src + 4);
    *(bf16x8*)&edgeT[(((size_t)a << 14) + b) * 256 + (d8 << 3)] = cvt8(v0, v1);
}

// ---- fused main. LDS 64KB -> 2 blocks/CU.
__global__ __launch_bounds__(512, 4)
void fused_main(const float* __restrict__ img, const float* __restrict__ bias,
                const bf16_t* __restrict__ edgeT,
                const bf16_t* __restrict__ W1f, const bf16_t* __restrict__ W2f,
                const bf16_t* __restrict__ Pff, const bf16_t* __restrict__ Pbf,
                const float* __restrict__ sw, float* __restrict__ out)
{
    __shared__ bf16_t E[2][32 * 256];   // 2 x 16 KB edge dbuf
    __shared__ bf16_t G[32 * 256];      // 16 KB agg
    __shared__ bf16_t R[32 * 256];      // 16 KB attr bf16

    const int tid = threadIdx.x;
    const int lane = tid & 63;
    const int wc = tid >> 6;            // 0..7: 32-col slice
    const int lr = lane & 15;
    const int lhi = lane >> 4;
    const int brow0 = blockIdx.x * 32;
    const int sr = tid >> 4;            // staging row 0..31
    const int c16 = (tid & 15) * 16;    // staging col base

    // ---- prologue: img -> E[0] (bf16 swz)
    {
        const float* ip = img + (size_t)(brow0 + sr) * ND + c16;
        f32x4 v0 = *(const f32x4*)(ip + 0), v1 = *(const f32x4*)(ip + 4);
        f32x4 v2 = *(const f32x4*)(ip + 8), v3 = *(const f32x4*)(ip + 12);
        *(bf16x8*)&E[0][swz(sr, c16)] = cvt8(v0, v1);
        *(bf16x8*)&E[0][swz(sr, c16 + 8)] = cvt8(v2, v3);
    }
    __syncthreads();

    // ---- T = img @ W1^T + bias (W1 in regs, then overwritten by W2)
    bf16x8 Wr[2][8];
#pragma unroll
    for (int ni = 0; ni < 2; ++ni)
#pragma unroll
        for (int ks = 0; ks < 8; ++ks)
            Wr[ni][ks] = *(const bf16x8*)&W1f[(((wc * 2 + ni) * 8 + ks) * 64 + lane) * 8];

    f32x4 T[2][2];
#pragma unroll
    for (int ni = 0; ni < 2; ++ni) {
        float bz = bias[wc * 32 + ni * 16 + lr];
        T[0][ni] = (f32x4){bz, bz, bz, bz};
        T[1][ni] = (f32x4){bz, bz, bz, bz};
    }
    gemm32r(&E[0][0], Wr, T, lane);

#pragma unroll
    for (int ni = 0; ni < 2; ++ni)
#pragma unroll
        for (int ks = 0; ks < 8; ++ks)
            Wr[ni][ks] = *(const bf16x8*)&W2f[(((wc * 2 + ni) * 8 + ks) * 64 + lane) * 8];
    __syncthreads();                    // E[0] free

    // ---- edge(a=0) -> E[0] (plain loads: edgeT is L3-resident)
    {
        const bf16_t* ep = edgeT + ((size_t)0 * NB + brow0 + sr) * ND + c16;
        *(bf16x8*)&E[0][swz(sr, c16)] = *(const bf16x8*)ep;
        *(bf16x8*)&E[0][swz(sr, c16 + 8)] = *(const bf16x8*)(ep + 8);
    }
    __syncthreads();

    f32x4 indiv[2][2];
#pragma unroll
    for (int mi = 0; mi < 2; ++mi)
#pragma unroll
        for (int ni = 0; ni < 2; ++ni)
            indiv[mi][ni] = (f32x4){0.f, 0.f, 0.f, 0.f};

    for (int a = 0; a < NA; ++a) {
        const int cur = a & 1;
        const bool pf = (a + 1 < NA);
        f32x4 acc[2][2];

        // ---- phase 1: issue edge(a+1) loads; GEMM1 = T + edge @ W2^T (regs B)
        bf16x8 elo, ehi;
        if (pf) {
            const bf16_t* ep = edgeT + ((size_t)(a + 1) * NB + brow0 + sr) * ND + c16;
            elo = *(const bf16x8*)ep;
            ehi = *(const bf16x8*)(ep + 8);
        }
#pragma unroll
        for (int mi = 0; mi < 2; ++mi)
#pragma unroll
            for (int ni = 0; ni < 2; ++ni)
                acc[mi][ni] = T[mi][ni];
        gemm32r(&E[cur][0], Wr, acc, lane);
#pragma unroll
        for (int mi = 0; mi < 2; ++mi)
#pragma unroll
            for (int ni = 0; ni < 2; ++ni)
#pragma unroll
                for (int j = 0; j < 4; ++j)
                    G[swz(mi * 16 + lhi * 4 + j, wc * 32 + ni * 16 + lr)] = (bf16_t)acc[mi][ni][j];
        if (pf) {   // commit edge(a+1); latency hidden under GEMM1
            *(bf16x8*)&E[cur ^ 1][swz(sr, c16)] = elo;
            *(bf16x8*)&E[cur ^ 1][swz(sr, c16 + 8)] = ehi;
        }
        __syncthreads();

        // ---- phase 2: attr = agg @ Pf[a] -> R (bf16 swz) only
#pragma unroll
        for (int mi = 0; mi < 2; ++mi)
#pragma unroll
            for (int ni = 0; ni < 2; ++ni)
                acc[mi][ni] = (f32x4){0.f, 0.f, 0.f, 0.f};
        gemm32g(&G[0], Pff + (size_t)a * 65536, acc, lane, wc);
#pragma unroll
        for (int mi = 0; mi < 2; ++mi)
#pragma unroll
            for (int ni = 0; ni < 2; ++ni)
#pragma unroll
                for (int j = 0; j < 4; ++j)
                    R[swz(mi * 16 + lhi * 4 + j, wc * 32 + ni * 16 + lr)] = (bf16_t)acc[mi][ni][j];
        __syncthreads();

        // ---- phase 3: attr readback -> full-line nt fp32 stores;
        //      GEMM3: proj = relu(attr @ Pb[a]); indiv += proj * sw[a]
        {
            float* op = out + (size_t)brow0 * (NA * ND) + (size_t)a * ND;
#pragma unroll
            for (int h = 0; h < 2; ++h) {
                int r = (tid >> 5) + h * 16;
                int ce = (tid & 31) * 8;
                bf16x8 v = *(const bf16x8*)&R[swz(r, ce)];
                f32x4 lo = {(float)v[0], (float)v[1], (float)v[2], (float)v[3]};
                f32x4 hi = {(float)v[4], (float)v[5], (float)v[6], (float)v[7]};
                float* p = op + (size_t)r * (NA * ND) + ce;
                __builtin_nontemporal_store(lo, (f32x4*)p);
                __builtin_nontemporal_store(hi, (f32x4*)(p + 4));
            }
        }
#pragma unroll
        for (int mi = 0; mi < 2; ++mi)
#pragma unroll
            for (int ni = 0; ni < 2; ++ni)
                acc[mi][ni] = (f32x4){0.f, 0.f, 0.f, 0.f};
        gemm32g(&R[0], Pbf + (size_t)a * 65536, acc, lane, wc);
        const float swa = sw[a];
#pragma unroll
        for (int mi = 0; mi < 2; ++mi)
#pragma unroll
            for (int ni = 0; ni < 2; ++ni)
#pragma unroll
                for (int j = 0; j < 4; ++j)
                    indiv[mi][ni][j] += fmaxf(acc[mi][ni][j], 0.f) * swa;
        __syncthreads();
    }

    // ---- individual_embeddings (plain scattered stores; L2 aggregates)
#pragma unroll
    for (int mi = 0; mi < 2; ++mi)
#pragma unroll
        for (int ni = 0; ni < 2; ++ni)
#pragma unroll
            for (int j = 0; j < 4; ++j) {
                int r = mi * 16 + lhi * 4 + j;
                int c = wc * 32 + ni * 16 + lr;
                out[(size_t)NB * NA * ND + (size_t)(brow0 + r) * ND + c] = indiv[mi][ni][j];
            }
}

extern "C" void kernel_launch(void* const* d_in, const int* in_sizes, int n_in,
                              void* d_out, int out_size, void* d_ws, size_t ws_size,
                              hipStream_t stream)
{
    const float* img  = (const float*)d_in[0];
    const float* edge = (const float*)d_in[1];
    const float* Wagg = (const float*)d_in[2];
    const float* bagg = (const float*)d_in[3];
    const float* Pf   = (const float*)d_in[4];
    const float* Pb   = (const float*)d_in[5];
    const float* sw   = (const float*)d_in[6];
    float* out = (float*)d_out;

    char* ws = (char*)d_ws;
    bf16_t* W1f = (bf16_t*)(ws);                   // 128 KB fragment layout
    bf16_t* W2f = (bf16_t*)(ws + 131072);          // 128 KB
    bf16_t* Pff = (bf16_t*)(ws + 262144);          // 2 MB
    bf16_t* Pbf = (bf16_t*)(ws + 2359296);         // 2 MB
    bf16_t* edT = (bf16_t*)(ws + 4456448);         // 134.2 MB [a][b][d] bf16
    // temps alias edT (dead before edge_tr runs; stream-ordered)
    bf16_t* Ptf = (bf16_t*)(ws + 4456448);         // 2 MB row-major temp
    bf16_t* Ptb = (bf16_t*)(ws + 6553600);         // 2 MB row-major temp

    prep_wfrag<<<64, 256, 0, stream>>>(Wagg, W1f, W2f);
    transpose_P<<<2048, 256, 0, stream>>>(Pf, Pb, Ptf, Ptb);
    prep_pfrag<<<512, 256, 0, stream>>>(Ptf, Pff);
    prep_pfrag<<<512, 256, 0, stream>>>(Ptb, Pbf);
    edge_tr<<<32768, 256, 0, stream>>>(edge, edT);
    fused_main<<<NB / 32, 512, 0, stream>>>(img, bagg, edT, W1f, W2f, Pff, Pbf, sw, out);
}